// Round 6
// baseline (4955.886 us; speedup 1.0000x reference)
//
#include <hip/hip_runtime.h>
#include <hip/hip_fp16.h>

typedef __attribute__((ext_vector_type(2))) _Float16 half2v;
typedef __attribute__((ext_vector_type(2))) __fp16   fp16x2;

#define SEQ     512
#define THREADS 512

// ws layout (uint4 units for weights):
#define WX_OFF   0
#define WH_OFF   98304
#define WQR_OFF  196608          // Wq packed by ROWS: [512 m][64 uint4 of dd-pairs]
#define SYNC_OFF 3670016         // bytes: end of packed weights (229376*16)
// sync region (bytes):
//   flagH u32[256]@0 ; flagS u32[256]@1024
//   Hbuf  u32[2][64][256]@2048        (131072)
//   Pbuf  f32[2][8][32*192]@133120    (393216)  partial scores, [bid][192] per gid
//   pooled f32[64][512]@526336 ; fc1 f32[64][512]@657408   (end 788480)

__device__ inline unsigned int pack2f16(float a, float b) {
    fp16x2 p = __builtin_amdgcn_cvt_pkrtz(a, b);
    return __builtin_bit_cast(unsigned int, p);
}
__device__ inline float fdot2u(unsigned int a, unsigned int b, float acc) {
    return __builtin_amdgcn_fdot2(__builtin_bit_cast(half2v, a),
                                  __builtin_bit_cast(half2v, b), acc, false);
}
__device__ inline float dot4(uint4 h, uint4 w, float acc) {
    acc = fdot2u(h.x, w.x, acc); acc = fdot2u(h.y, w.y, acc);
    acc = fdot2u(h.z, w.z, acc); acc = fdot2u(h.w, w.w, acc);
    return acc;
}
__device__ inline float fsigmoid(float x) { return 1.f / (1.f + __expf(-x)); }
__device__ inline float ftanhf(float x) {
    float e = __expf(-2.f * fabsf(x));
    float t = (1.f - e) / (1.f + e);
    return copysignf(t, x);
}
__device__ inline void vmem_fence() { asm volatile("s_waitcnt vmcnt(0)" ::: "memory"); }
__device__ inline unsigned a_ld(unsigned* p) {
    return __hip_atomic_load(p, __ATOMIC_RELAXED, __HIP_MEMORY_SCOPE_AGENT);
}
__device__ inline void a_st(unsigned* p, unsigned v) {
    __hip_atomic_store(p, v, __ATOMIC_RELAXED, __HIP_MEMORY_SCOPE_AGENT);
}
__device__ inline float a_ldf(float* p) {
    return __hip_atomic_load(p, __ATOMIC_RELAXED, __HIP_MEMORY_SCOPE_AGENT);
}
__device__ inline void a_stf(float* p, float v) {
    __hip_atomic_store(p, v, __ATOMIC_RELAXED, __HIP_MEMORY_SCOPE_AGENT);
}

__global__ __launch_bounds__(256)
void pack_weights(const float* __restrict__ Wq,
                  const float* __restrict__ Wx,
                  const float* __restrict__ Wh,
                  uint4* __restrict__ ws) {
    int tid = blockIdx.x * blockDim.x + threadIdx.x;  // 0 .. 229375
    if (tid < 196608) {
        // Wx / Wh column-packed: [K/8][1536] uint4, pairs along K
        const float* src; uint4* dst; int idx;
        if (tid < 98304) { src = Wx; dst = ws + WX_OFF; idx = tid; }
        else             { src = Wh; dst = ws + WH_OFF; idx = tid - 98304; }
        int m4 = idx / 1536;
        int c  = idx - m4 * 1536;
        const float* s = src + (size_t)(m4 * 8) * 1536 + c;
        uint4 o;
        o.x = pack2f16(s[0 * 1536], s[1 * 1536]);
        o.y = pack2f16(s[2 * 1536], s[3 * 1536]);
        o.z = pack2f16(s[4 * 1536], s[5 * 1536]);
        o.w = pack2f16(s[6 * 1536], s[7 * 1536]);
        dst[idx] = o;
    } else {
        // Wq row-packed: [512 m][64 uint4], pairs along dd (columns)
        int idx = tid - 196608;            // 0 .. 32767
        int m = idx >> 6, q = idx & 63;
        const float* s = Wq + (size_t)m * 512 + q * 8;
        uint4 o;
        o.x = pack2f16(s[0], s[1]); o.y = pack2f16(s[2], s[3]);
        o.z = pack2f16(s[4], s[5]); o.w = pack2f16(s[6], s[7]);
        ws[WQR_OFF + idx] = o;
    }
}

// 256 blocks. gid = blk & 7 (XCD-local group heuristic), bid = blk >> 3.
// Group gid owns batches 8*gid..8*gid+7; block bid owns h/gate cols [bid*16,+16)
// and Wq ROWS [bid*16,+16). One sync per step: publish (h(t), pscores(t+1)).
__global__ __launch_bounds__(THREADS)
void gru_scan(const int* __restrict__ xtok, const float* __restrict__ emb,
              const uint4* __restrict__ wsp, const float* __restrict__ bx,
              const float* __restrict__ bh, const float* __restrict__ W1,
              const float* __restrict__ b1, const float* __restrict__ W2,
              const float* __restrict__ b2, float* __restrict__ out)
{
    const int blk  = blockIdx.x;
    const int gid  = blk & 7;
    const int bid  = blk >> 3;
    const int tid  = threadIdx.x;
    const int lane = tid & 63;
    const int wid  = tid >> 6;
    const int colsub = lane & 7;
    const int bp     = (lane >> 3) & 3;
    const int chsub  = lane >> 5;

    char* syncb = (char*)wsp + SYNC_OFF;
    unsigned* flagH = (unsigned*)syncb;
    unsigned* flagS = (unsigned*)(syncb + 1024);
    unsigned* Hbuf  = (unsigned*)(syncb + 2048);
    float* Pbuf     = (float*)(syncb + 133120);
    float* pooled_g = (float*)(syncb + 526336);
    float* fc1_g    = (float*)(syncb + 657408);

    __shared__ uint4 lds_Wh[64][48];    // Wh col-slice (r,z,n x16)
    __shared__ uint4 lds_Wx[64][48];    // Wx col-slice
    __shared__ uint4 lds_Wqr[16][64];   // Wq row-slice, dd-pairs packed
    __shared__ uint4 lds_h4[8][66];     // full h(t-1), f16-packed
    __shared__ uint4 lds_ctx[8][66];    // ctx, f16-packed
    __shared__ float red[8][48][9];
    __shared__ float sum[48][9];
    __shared__ float kap[16][8][24];    // kappa slice: [m][b][n*3+g]
    __shared__ float hsl[8][17];        // own h-slice f32: [b][m]
    __shared__ float scmem[8][24];      // summed raw scores
    __shared__ float a_lds[8][8][3];

    // ---- persistent weight slices -> LDS ----
    for (int i = tid; i < 64 * 48; i += THREADS) {
        int ch = i / 48, cl = i - ch * 48;
        int g = cl >> 4, c = cl & 15;
        lds_Wh[ch][cl] = wsp[WH_OFF + ch * 1536 + g * 512 + bid * 16 + c];
        lds_Wx[ch][cl] = wsp[WX_OFF + ch * 1536 + g * 512 + bid * 16 + c];
    }
    for (int i = tid; i < 16 * 64; i += THREADS) {
        int m = i >> 6, q = i & 63;
        lds_Wqr[m][q] = wsp[WQR_OFF + (bid * 16 + m) * 64 + q];
    }

    float bxr = 0, bxz = 0, bxn = 0, bhr = 0, bhz = 0, bhn = 0;
    if (tid < 128) {
        int c = tid >> 3;
        int cg = bid * 16 + c;
        bxr = bx[cg]; bxz = bx[512 + cg]; bxn = bx[1024 + cg];
        bhr = bh[cg]; bhz = bh[512 + cg]; bhn = bh[1024 + cg];
    }

    // rolling window rows in registers: r0=row(t-2), r1=row(t-1), r2=row(t)
    const int b  = wid;
    const int gb = gid * 8 + b;
    float4 r0a = {0,0,0,0}, r0b = {0,0,0,0};
    float4 r1a = {0,0,0,0}, r1b = {0,0,0,0};
    float4 r2a, r2b;
    { int tk = xtok[gb * SEQ];
      const float4* p = (const float4*)(emb + (size_t)tk * 512 + lane * 8);
      r2a = p[0]; r2b = p[1]; }
    unsigned pk1[4] = {0, 0, 0, 0};
    unsigned pk2[4];
    pk2[0] = pack2f16(r2a.x, r2a.y); pk2[1] = pack2f16(r2a.z, r2a.w);
    pk2[2] = pack2f16(r2b.x, r2b.y); pk2[3] = pack2f16(r2b.z, r2b.w);

    float hprev = 0.f, pooledv = 0.f;
    __syncthreads();

    for (int t = 0; t < SEQ; ++t) {
        const int par = t & 1;

        // ---- prefetch row t+1 (r3) ----
        float4 r3a = {0,0,0,0}, r3b = {0,0,0,0};
        if (t + 1 < SEQ) {
            int tk = xtok[gb * SEQ + t + 1];
            const float4* p = (const float4*)(emb + (size_t)tk * 512 + lane * 8);
            r3a = p[0]; r3b = p[1];
        }
        unsigned pk3[4];
        pk3[0] = pack2f16(r3a.x, r3a.y); pk3[1] = pack2f16(r3a.z, r3a.w);
        pk3[2] = pack2f16(r3b.x, r3b.y); pk3[3] = pack2f16(r3b.z, r3b.w);

        // ---- kappa(t+1) for scores(t+1): window rows pk1(t-1), pk2(t), pk3(t+1)
        //      kap[m][b][n*3+g] = sum_{dd in head n} Wq[bid*16+m, dd] * win[g, dd]
        //      (h-independent; overlaps the flag wait)
        {
            const int s  = lane & 7;
            const int n3 = (lane >> 3) * 3;
            #pragma unroll
            for (int m = 0; m < 16; ++m) {
                uint4 wq = lds_Wqr[m][lane];
                float p0 = fdot2u(pk1[0], wq.x, 0.f);
                p0 = fdot2u(pk1[1], wq.y, p0);
                p0 = fdot2u(pk1[2], wq.z, p0);
                p0 = fdot2u(pk1[3], wq.w, p0);
                float p1 = fdot2u(pk2[0], wq.x, 0.f);
                p1 = fdot2u(pk2[1], wq.y, p1);
                p1 = fdot2u(pk2[2], wq.z, p1);
                p1 = fdot2u(pk2[3], wq.w, p1);
                float p2 = fdot2u(pk3[0], wq.x, 0.f);
                p2 = fdot2u(pk3[1], wq.y, p2);
                p2 = fdot2u(pk3[2], wq.z, p2);
                p2 = fdot2u(pk3[3], wq.w, p2);
                p0 += __shfl_xor(p0, 1); p1 += __shfl_xor(p1, 1); p2 += __shfl_xor(p2, 1);
                p0 += __shfl_xor(p0, 2); p1 += __shfl_xor(p1, 2); p2 += __shfl_xor(p2, 2);
                p0 += __shfl_xor(p0, 4); p1 += __shfl_xor(p1, 4); p2 += __shfl_xor(p2, 4);
                if (s == (m & 7)) {
                    float* kp = &kap[m][b][n3];
                    kp[0] = p0; kp[1] = p1; kp[2] = p2;
                }
            }
        }

        // ---- ONE wait: all 32 blocks published (h(t-1), pscores(t)) ----
        if (wid == 0) {
            bool done = lane >= 32;
            while (!__all(done)) {
                if (!done) done = (a_ld(&flagH[gid * 32 + lane]) >= (unsigned)t);
                if (!__all(done)) __builtin_amdgcn_s_sleep(1);
            }
        }
        __syncthreads();   // S1

        // ---- P1: load full h(t-1) + sum partial scores ----
        {
            int bb = tid >> 6, ch = tid & 63;
            unsigned* s = Hbuf + (size_t)(par ^ 1) * 16384 + (gid * 8 + bb) * 256 + ch * 4;
            uint4 v;
            v.x = a_ld(s); v.y = a_ld(s + 1); v.z = a_ld(s + 2); v.w = a_ld(s + 3);
            lds_h4[bb][ch] = v;
        }
        if (tid < 192) {
            float* pb = Pbuf + (size_t)(par ^ 1) * 8 * 6144 + gid * 6144;
            float sc = 0.f;
            #pragma unroll
            for (int k = 0; k < 32; ++k) sc += a_ldf(pb + k * 192 + tid);
            scmem[tid / 24][tid % 24] = sc;
        }
        __syncthreads();   // S2

        // ---- P2: GEMM-gh (all) | softmax (64 thr) ----
        {
            float ag[12];
            #pragma unroll
            for (int i = 0; i < 12; ++i) ag[i] = 0.f;
            int ch0 = wid * 8 + chsub * 4;
            #pragma unroll
            for (int i = 0; i < 4; ++i) {
                int ch = ch0 + i;
                uint4 h0 = lds_h4[bp][ch], h1 = lds_h4[bp + 4][ch];
                #pragma unroll
                for (int j = 0; j < 6; ++j) {
                    uint4 w = lds_Wh[ch][colsub + 8 * j];
                    ag[j]     = dot4(h0, w, ag[j]);
                    ag[6 + j] = dot4(h1, w, ag[6 + j]);
                }
            }
            #pragma unroll
            for (int i = 0; i < 12; ++i) ag[i] += __shfl_xor(ag[i], 32);
            if (chsub == 0) {
                #pragma unroll
                for (int j = 0; j < 6; ++j) {
                    red[wid][colsub + 8 * j][bp]     = ag[j];
                    red[wid][colsub + 8 * j][bp + 4] = ag[6 + j];
                }
            }
        }
        if (tid < 64) {
            int bb = tid >> 3, n = tid & 7;
            float s0 = scmem[bb][n * 3 + 0] * 0.125f;
            float s1 = scmem[bb][n * 3 + 1] * 0.125f;
            float s2 = scmem[bb][n * 3 + 2] * 0.125f;
            float mx = fmaxf(s0, fmaxf(s1, s2));
            float e0 = __expf(s0 - mx), e1 = __expf(s1 - mx), e2 = __expf(s2 - mx);
            float inv = 1.f / (e0 + e1 + e2);
            a_lds[bb][n][0] = e0 * inv; a_lds[bb][n][1] = e1 * inv; a_lds[bb][n][2] = e2 * inv;
        }
        __syncthreads();   // S3

        // ---- P3: ctx build (regs r0,r1,r2) | gh-sum ----
        {
            int head = lane >> 3;
            float a0 = a_lds[b][head][0], a1 = a_lds[b][head][1], a2 = a_lds[b][head][2];
            float c0 = a0 * r0a.x + a1 * r1a.x + a2 * r2a.x;
            float c1 = a0 * r0a.y + a1 * r1a.y + a2 * r2a.y;
            float c2 = a0 * r0a.z + a1 * r1a.z + a2 * r2a.z;
            float c3 = a0 * r0a.w + a1 * r1a.w + a2 * r2a.w;
            float c4 = a0 * r0b.x + a1 * r1b.x + a2 * r2b.x;
            float c5 = a0 * r0b.y + a1 * r1b.y + a2 * r2b.y;
            float c6 = a0 * r0b.z + a1 * r1b.z + a2 * r2b.z;
            float c7 = a0 * r0b.w + a1 * r1b.w + a2 * r2b.w;
            uint4 pk;
            pk.x = pack2f16(c0, c1); pk.y = pack2f16(c2, c3);
            pk.z = pack2f16(c4, c5); pk.w = pack2f16(c6, c7);
            lds_ctx[b][lane] = pk;
        }
        if (tid < 384) {
            int col = tid >> 3, bb = tid & 7;
            float s = red[0][col][bb];
            #pragma unroll
            for (int k = 1; k < 8; ++k) s += red[k][col][bb];
            sum[col][bb] = s;
        }
        __syncthreads();   // S4

        // ---- P4: GEMM2 gx ----
        {
            float acx[12];
            #pragma unroll
            for (int i = 0; i < 12; ++i) acx[i] = 0.f;
            int ch0 = wid * 8 + chsub * 4;
            #pragma unroll
            for (int i = 0; i < 4; ++i) {
                int ch = ch0 + i;
                uint4 c0 = lds_ctx[bp][ch];
                uint4 c1 = lds_ctx[bp + 4][ch];
                #pragma unroll
                for (int j = 0; j < 6; ++j) {
                    uint4 w = lds_Wx[ch][colsub + 8 * j];
                    acx[j]     = dot4(c0, w, acx[j]);
                    acx[6 + j] = dot4(c1, w, acx[6 + j]);
                }
            }
            #pragma unroll
            for (int i = 0; i < 12; ++i) acx[i] += __shfl_xor(acx[i], 32);
            if (chsub == 0) {
                #pragma unroll
                for (int j = 0; j < 6; ++j) {
                    red[wid][colsub + 8 * j][bp]     = acx[j];
                    red[wid][colsub + 8 * j][bp + 4] = acx[6 + j];
                }
            }
        }
        __syncthreads();   // S5

        // ---- P5: GRU pointwise, h-slice to LDS + Hbuf ----
        if (tid < 128) {
            int c = tid >> 3, bb = tid & 7;
            float gxr = bxr, gxz = bxz, gxn = bxn;
            #pragma unroll
            for (int k = 0; k < 8; ++k) {
                gxr += red[k][c][bb];
                gxz += red[k][16 + c][bb];
                gxn += red[k][32 + c][bb];
            }
            float ghr = sum[c][bb] + bhr;
            float ghz = sum[16 + c][bb] + bhz;
            float ghn = sum[32 + c][bb] + bhn;
            float r = fsigmoid(gxr + ghr);
            float z = fsigmoid(gxz + ghz);
            float n = ftanhf(gxn + r * ghn);
            float hnew = (1.f - z) * n + z * hprev;
            hprev = hnew; pooledv += hnew;
            hsl[bb][c] = hnew;
            float hnext = __shfl_down(hnew, 8);
            if ((c & 1) == 0)
                a_st(&Hbuf[(size_t)par * 16384 + (gid * 8 + bb) * 256 + bid * 8 + (c >> 1)],
                     pack2f16(hnew, hnext));
        }
        __syncthreads();   // S6

        // ---- P6: partial scores(t+1) = h-slice . kappa ----
        if (tid < 192) {
            int bb = tid / 24, r = tid % 24;
            float p = 0.f;
            #pragma unroll
            for (int m = 0; m < 16; ++m) p += hsl[bb][m] * kap[m][bb][r];
            a_stf(Pbuf + (size_t)par * 8 * 6144 + gid * 6144 + bid * 192 + tid, p);
        }
        vmem_fence();
        __syncthreads();   // S7
        if (tid == 0) a_st(&flagH[gid * 32 + bid], (unsigned)(t + 1));

        // ---- roll window regs ----
        r0a = r1a; r0b = r1b; r1a = r2a; r1b = r2b; r2a = r3a; r2b = r3b;
        pk1[0] = pk2[0]; pk1[1] = pk2[1]; pk1[2] = pk2[2]; pk1[3] = pk2[3];
        pk2[0] = pk3[0]; pk2[1] = pk3[1]; pk2[2] = pk3[2]; pk2[3] = pk3[3];
    }

    // ======== epilogue: pooled -> relu -> FC1 -> FC2 ========
    float* stage = (float*)&lds_Wh[0][0];   // reuse weight LDS as [8][512] staging
    if (tid < 128) {
        int c = tid >> 3, bb = tid & 7;
        a_stf(&pooled_g[(gid * 8 + bb) * 512 + bid * 16 + c], fmaxf(pooledv, 0.f));
    }
    vmem_fence();
    __syncthreads();
    if (tid == 0) a_st(&flagS[gid * 32 + bid], (unsigned)(SEQ + 1));
    if (wid == 0) {
        bool done = lane >= 32;
        while (!__all(done)) {
            if (!done) done = (a_ld(&flagS[gid * 32 + lane]) >= (unsigned)(SEQ + 1));
            if (!__all(done)) __builtin_amdgcn_s_sleep(1);
        }
    }
    __syncthreads();

    for (int i = tid; i < 8 * 512; i += THREADS) {
        int bb = i >> 9, k = i & 511;
        stage[bb * 512 + k] = a_ldf(&pooled_g[(gid * 8 + bb) * 512 + k]);
    }
    __syncthreads();

    if (tid < 128) {
        int c = tid >> 3, bb = tid & 7;
        int cg = bid * 16 + c;
        const float* pr = stage + bb * 512;
        float acc1 = b1[cg];
        for (int k = 0; k < 512; ++k) acc1 += pr[k] * W1[(size_t)k * 512 + cg];
        a_stf(&fc1_g[(gid * 8 + bb) * 512 + cg], acc1);
    }
    vmem_fence();
    __syncthreads();
    if (tid == 0) a_st(&flagH[gid * 32 + bid], (unsigned)(SEQ + 2));

    if (bid == 0) {
        if (wid == 0) {
            bool done = lane >= 32;
            while (!__all(done)) {
                if (!done) done = (a_ld(&flagH[gid * 32 + lane]) >= (unsigned)(SEQ + 2));
                if (!__all(done)) __builtin_amdgcn_s_sleep(1);
            }
        }
        __syncthreads();
        for (int i = tid; i < 8 * 512; i += THREADS) {
            int bb = i >> 9, k = i & 511;
            stage[bb * 512 + k] = a_ldf(&fc1_g[(gid * 8 + bb) * 512 + k]);
        }
        __syncthreads();
        if (tid < 80) {
            int bb = tid / 10, cls = tid - bb * 10;
            const float* fr = stage + bb * 512;
            float a2 = b2[cls];
            for (int k = 0; k < 512; ++k) a2 += fr[k] * W2[k * 10 + cls];
            out[(gid * 8 + bb) * 10 + cls] = a2;
        }
    }
}

extern "C" void kernel_launch(void* const* d_in, const int* in_sizes, int n_in,
                              void* d_out, int out_size, void* d_ws, size_t ws_size,
                              hipStream_t stream) {
    const int*   x   = (const int*)d_in[0];
    const float* emb = (const float*)d_in[1];
    const float* Wq  = (const float*)d_in[2];
    const float* Wx  = (const float*)d_in[3];
    const float* Wh  = (const float*)d_in[4];
    const float* bx  = (const float*)d_in[5];
    const float* bh  = (const float*)d_in[6];
    const float* W1  = (const float*)d_in[7];
    const float* b1  = (const float*)d_in[8];
    const float* W2  = (const float*)d_in[9];
    const float* b2  = (const float*)d_in[10];
    uint4* wsp = (uint4*)d_ws;
    float* outp = (float*)d_out;

    hipLaunchKernelGGL(pack_weights, dim3(896), dim3(256), 0, stream, Wq, Wx, Wh, wsp);
    hipMemsetAsync((char*)d_ws + SYNC_OFF, 0, 526336, stream);

    void* args[] = { (void*)&x, (void*)&emb, (void*)&wsp, (void*)&bx, (void*)&bh,
                     (void*)&W1, (void*)&b1, (void*)&W2, (void*)&b2, (void*)&outp };
    hipError_t e = hipLaunchCooperativeKernel((void*)gru_scan, dim3(256), dim3(THREADS),
                                              args, 0, stream);
    if (e != hipSuccess) {
        hipLaunchKernelGGL(gru_scan, dim3(256), dim3(THREADS), 0, stream,
                           x, emb, wsp, bx, bh, W1, b1, W2, b2, outp);
    }
}